// Round 12
// baseline (2146.155 us; speedup 1.0000x reference)
//
#include <hip/hip_runtime.h>

// SDGCN32: 31-layer GCN, N=100k, E=3.2M, F=32.  == R10 configuration (verified pass, 2144us) ==
//  - hs = dis*h carried FP32, row-major [n][32] (fp16 carrier fails 31-layer error amp)
//  - CSR per (dst, src-bucket), NB=4 (R7 optimum; NB=8 and NB=1 both worse)
//  - CSR built via two-level binning (R10: kills k_fill's 194MB partial-line write amp)
//  - k_gcn (R7): wave = 8 nodes x 8 quads; lanes (i,0..7) walk node i's segment
//    in lockstep (one 128B line/edge, coalesced); register accumulation, unroll-4;
//    buckets swept in phase (__syncthreads) -> per-XCD L2 working set ~= one 4MiB chunk.
//  - k_x0: R10 version (1 node/wave). NOTE: an 8-node/wave rewrite (R11) timed 95us faster
//    but deterministically diverged on graph replays while passing the first launch —
//    mechanism unidentified; quarantined. Do not re-apply without understanding it.
//  - out accumulated online: out += mynorm(x_j)@Mn_j (+ raw x_j@Rw_j, j in {1,16})

#define NB 4        // src buckets
#define BSHIFT 15   // bucket = src >> 15 (32768 nodes = 4 MiB fp32 chunk)
#define CSH 9       // coarse bin = dst >> 9 (512 nodes)

__device__ __forceinline__ float shflx(float v, int m) { return __shfl_xor(v, m, 64); }

// ---------- pass A1: coarse histogram ----------
__global__ __launch_bounds__(256) void k_chist(const int* __restrict__ dst, int E,
                                               int* __restrict__ gcnt, int G1) {
    __shared__ int lh[256];
    lh[threadIdx.x] = 0;
    __syncthreads();
    int chunk = (E + gridDim.x - 1) / gridDim.x;
    int s0 = blockIdx.x * chunk, s1 = min(E, s0 + chunk);
    for (int e = s0 + threadIdx.x; e < s1; e += 256)
        atomicAdd(&lh[dst[e] >> CSH], 1);
    __syncthreads();
    if (threadIdx.x < G1 && lh[threadIdx.x])
        atomicAdd(&gcnt[threadIdx.x], lh[threadIdx.x]);
}

// ---------- pass A2: scan coarse bins (G1 <= 256) ----------
__global__ void k_cscan(const int* __restrict__ gcnt, int* __restrict__ gptr,
                        int* __restrict__ gcur, int G1, int E) {
    __shared__ int s[256];
    int t = threadIdx.x;
    int v = (t < G1) ? gcnt[t] : 0;
    s[t] = v;
    __syncthreads();
    for (int off = 1; off < 256; off <<= 1) {
        int tv = (t >= off) ? s[t - off] : 0;
        __syncthreads();
        s[t] += tv;
        __syncthreads();
    }
    if (t < G1) { int ex = s[t] - v; gptr[t] = ex; gcur[t] = ex; }
    if (t == 0) gptr[G1] = E;
}

// ---------- pass A3: reservation scatter of packed (src | ldst<<17) ----------
__global__ __launch_bounds__(256) void k_cscatter(const int* __restrict__ src,
                                                  const int* __restrict__ dst, int E,
                                                  int* __restrict__ gcur,
                                                  int* __restrict__ tmp, int G1) {
    __shared__ int lh[256], lc[256];
    lh[threadIdx.x] = 0;
    __syncthreads();
    int chunk = (E + gridDim.x - 1) / gridDim.x;
    int s0 = blockIdx.x * chunk, s1 = min(E, s0 + chunk);
    for (int e = s0 + threadIdx.x; e < s1; e += 256)
        atomicAdd(&lh[dst[e] >> CSH], 1);
    __syncthreads();
    if (threadIdx.x < G1) {
        int c = lh[threadIdx.x];
        lc[threadIdx.x] = c ? atomicAdd(&gcur[threadIdx.x], c) : 0;
    }
    __syncthreads();
    for (int e = s0 + threadIdx.x; e < s1; e += 256) {
        int d = dst[e];
        int pos = atomicAdd(&lc[d >> CSH], 1);
        tmp[pos] = src[e] | ((d & ((1 << CSH) - 1)) << 17);
    }
}

// ---------- pass B: per coarse group -> fine CSR (rp4, csr, dis) ----------
__global__ __launch_bounds__(256) void k_build(const int* __restrict__ tmp,
                                               const int* __restrict__ gptr,
                                               int* __restrict__ rp4,
                                               int* __restrict__ csr,
                                               float* __restrict__ dis,
                                               int N, int M) {
    __shared__ int h[2048];     // fine bins: 512 nodes x NB
    __shared__ int c[2048];
    __shared__ int s[256];
    int g = blockIdx.x;
    int gb = gptr[g], ge = gptr[g + 1];
    int t = threadIdx.x;
#pragma unroll
    for (int k = 0; k < 8; ++k) h[t * 8 + k] = 0;
    __syncthreads();
    for (int e = gb + t; e < ge; e += 256) {
        int w = tmp[e];
        int srcv = w & 0x1FFFF, ldst = w >> 17;
        atomicAdd(&h[ldst * NB + (srcv >> BSHIFT)], 1);
    }
    __syncthreads();
    int base8 = t * 8;
    int loc[8], sum = 0;
#pragma unroll
    for (int k = 0; k < 8; ++k) { loc[k] = h[base8 + k]; sum += loc[k]; }
    s[t] = sum;
    __syncthreads();
    for (int off = 1; off < 256; off <<= 1) {
        int tv = (t >= off) ? s[t - off] : 0;
        __syncthreads();
        s[t] += tv;
        __syncthreads();
    }
    int run = s[t] - sum;
    int rowbase = g * 2048;
#pragma unroll
    for (int k = 0; k < 8; ++k) {
        int i = base8 + k;
        c[i] = run;
        int ig = rowbase + i;
        if (ig <= M) rp4[ig] = gb + run;
        run += loc[k];
    }
    __syncthreads();
    for (int e = gb + t; e < ge; e += 256) {
        int w = tmp[e];
        int srcv = w & 0x1FFFF, ldst = w >> 17;
        int pos = atomicAdd(&c[ldst * NB + (srcv >> BSHIFT)], 1);
        csr[gb + pos] = srcv;
    }
    // degrees -> dis
    int nodebase = g << CSH;
    for (int ln = t; ln < (1 << CSH); ln += 256) {
        int n = nodebase + ln;
        if (n < N) {
            int d = h[ln * NB] + h[ln * NB + 1] + h[ln * NB + 2] + h[ln * NB + 3];
            dis[n] = rsqrtf((float)d + 1.0f);
        }
    }
    if (g == gridDim.x - 1 && t == 0) rp4[M] = ge;   // ge == E for last group
}

// ---------- coefficients, layout [j][o][c] ----------
__global__ void k_mnorm(const float* __restrict__ W2, float* __restrict__ Mn,
                        float* __restrict__ Rw) {
    int idx = blockIdx.x * blockDim.x + threadIdx.x;
    if (idx >= 32 * 32 * 10) return;
    int c = idx % 32, o = (idx / 32) % 10, j = idx / 320;
    float v = 0.f;
    if (j >= 2 && j != 16) v += W2[(32 * j + c) * 10 + o];
    if (j <= 29 && j != 14) v -= W2[(32 * (j + 2) + c) * 10 + o];
    Mn[idx] = v;
    Rw[idx] = (j == 0 || j == 1 || j == 16) ? W2[(32 * j + c) * 10 + o] : 0.f;
}

// ---------- layer 0: x0 = mynorm(relu(x@W1+b1)); out init; hs row-major ----------
__global__ __launch_bounds__(256) void k_x0(
    const float* __restrict__ x, const float* __restrict__ W1, const float* __restrict__ b1,
    const float* __restrict__ W2, const float* __restrict__ b2, const float* __restrict__ M0,
    const float* __restrict__ dis, float* __restrict__ hs, float* __restrict__ out, int N)
{
    __shared__ float Ws[64 * 32];
    for (int i = threadIdx.x; i < 64 * 32; i += 256) Ws[i] = W1[i];
    __syncthreads();
    int wave = threadIdx.x >> 6;
    int lane = threadIdx.x & 63;
    int c = lane & 31, half = lane >> 5;
    int n = blockIdx.x * 4 + wave;
    if (n >= N) return;

    float xr = x[n * 64 + lane];
    float acc = 0.f;
#pragma unroll
    for (int kk = 0; kk < 32; ++kk) {
        float xv = __shfl(xr, half * 32 + kk, 64);
        acc += xv * Ws[(half * 32 + kk) * 32 + c];
    }
    acc += shflx(acc, 32);
    acc += b1[c];
    acc = fmaxf(acc, 0.f);
    float mn = acc, mx = acc;
#pragma unroll
    for (int m = 1; m <= 16; m <<= 1) { mn = fminf(mn, shflx(mn, m)); mx = fmaxf(mx, shflx(mx, m)); }
    float x0 = 2.f * (acc - mn) / (mx - mn + 1e-8f) - 1.f;
    float dn = dis[n];
    if (half == 0) hs[n * 32 + c] = dn * x0;
    mn = x0; mx = x0;
#pragma unroll
    for (int m = 1; m <= 16; m <<= 1) { mn = fminf(mn, shflx(mn, m)); mx = fmaxf(mx, shflx(mx, m)); }
    float n0 = 2.f * (x0 - mn) / (mx - mn + 1e-8f) - 1.f;
    float outv = 0.f;
#pragma unroll
    for (int o = 0; o < 10; ++o) {
        float t = x0 * W2[c * 10 + o] + n0 * M0[o * 32 + c];
#pragma unroll
        for (int m = 1; m <= 16; m <<= 1) t += shflx(t, m);
        if (lane == o) outv = t;
    }
    if (lane < 10) out[n * 10 + lane] = b2[lane] + outv;
}

// ---------- GCN layer: register-acc bucketed gather + parallel epilogue (R7) ----------
__global__ __launch_bounds__(256) void k_gcn(
    const float4* __restrict__ hs_in, float4* __restrict__ hs_out,
    const float* __restrict__ dis, const int* __restrict__ rp4,
    const int* __restrict__ csr,
    const float* __restrict__ W, const float* __restrict__ b,
    const float* __restrict__ Mn, const float* __restrict__ Rw,
    float* __restrict__ out, int N, int israw)
{
    __shared__ float Ws[1024];   // W [k][c]
    __shared__ float bs[32];
    __shared__ float Ms[320];    // Mn_j [o][c]
    __shared__ float Rs[320];    // Rw_j [o][c]
    for (int i = threadIdx.x; i < 1024; i += 256) Ws[i] = W[i];
    for (int i = threadIdx.x; i < 320; i += 256) { Ms[i] = Mn[i]; Rs[i] = Rw[i]; }
    if (threadIdx.x < 32) bs[threadIdx.x] = b[threadIdx.x];
    __syncthreads();

    int lane = threadIdx.x & 63;
    int q = lane & 7;            // channel quad c = 4q..4q+3
    int i8 = lane >> 3;          // node-sub 0..7
    int wave = threadIdx.x >> 6;
    int n = blockIdx.x * 32 + wave * 8 + i8;
    bool valid = (n < N);
    int nn = valid ? n : (N - 1);       // clamp: extra harmless loads only

    // self-loop term; lanes (i,0..7) -> 8 consecutive 128B rows = 1KB coalesced
    float4 acc = hs_in[(size_t)nn * 8 + q];

    int rbase = nn * NB;
    int rs = rp4[rbase];
    for (int p = 0; p < NB; ++p) {
        int re = rp4[rbase + p + 1];    // segment continuity: next rs = this re
        int e = rs;
        for (; e + 3 < re; e += 4) {
            int s0 = csr[e], s1 = csr[e + 1], s2 = csr[e + 2], s3 = csr[e + 3];
            float4 v0 = hs_in[(size_t)s0 * 8 + q];
            float4 v1 = hs_in[(size_t)s1 * 8 + q];
            float4 v2 = hs_in[(size_t)s2 * 8 + q];
            float4 v3 = hs_in[(size_t)s3 * 8 + q];
            acc.x += v0.x; acc.y += v0.y; acc.z += v0.z; acc.w += v0.w;
            acc.x += v1.x; acc.y += v1.y; acc.z += v1.z; acc.w += v1.w;
            acc.x += v2.x; acc.y += v2.y; acc.z += v2.z; acc.w += v2.w;
            acc.x += v3.x; acc.y += v3.y; acc.z += v3.z; acc.w += v3.w;
        }
        if (e + 1 < re) {
            int s0 = csr[e], s1 = csr[e + 1];
            float4 v0 = hs_in[(size_t)s0 * 8 + q];
            float4 v1 = hs_in[(size_t)s1 * 8 + q];
            acc.x += v0.x; acc.y += v0.y; acc.z += v0.z; acc.w += v0.w;
            acc.x += v1.x; acc.y += v1.y; acc.z += v1.z; acc.w += v1.w;
            e += 2;
        }
        if (e < re) {
            int s0 = csr[e];
            float4 v0 = hs_in[(size_t)s0 * 8 + q];
            acc.x += v0.x; acc.y += v0.y; acc.z += v0.z; acc.w += v0.w;
        }
        rs = re;
        __syncthreads();         // bucket phase alignment (uniform: all threads loop NB times)
    }

    float dn = dis[nn];
    float4 g = make_float4(dn * acc.x, dn * acc.y, dn * acc.z, dn * acc.w);

    // GEMM: xn[quad q of node i] = b + sum_k g_i[k] * W[k][4q..4q+3]
    const float4* W4 = (const float4*)Ws;
    float4 bb = ((const float4*)bs)[q];
    float4 xn = bb;
    int ibase = lane & 0x38;     // i8<<3
#pragma unroll
    for (int kp = 0; kp < 8; ++kp) {
        int sl = ibase | kp;     // lane holding quad kp of node i
        float gx = __shfl(g.x, sl, 64);
        float gy = __shfl(g.y, sl, 64);
        float gz = __shfl(g.z, sl, 64);
        float gw = __shfl(g.w, sl, 64);
        float4 w0 = W4[(kp * 4 + 0) * 8 + q];
        float4 w1 = W4[(kp * 4 + 1) * 8 + q];
        float4 w2 = W4[(kp * 4 + 2) * 8 + q];
        float4 w3 = W4[(kp * 4 + 3) * 8 + q];
        xn.x += gx * w0.x + gy * w1.x + gz * w2.x + gw * w3.x;
        xn.y += gx * w0.y + gy * w1.y + gz * w2.y + gw * w3.y;
        xn.z += gx * w0.z + gy * w1.z + gz * w2.z + gw * w3.z;
        xn.w += gx * w0.w + gy * w1.w + gz * w2.w + gw * w3.w;
    }

    if (valid)
        hs_out[(size_t)n * 8 + q] = make_float4(dn * xn.x, dn * xn.y, dn * xn.z, dn * xn.w);

    // mynorm over node's 32 channels: local 4, then butterfly over q bits (1,2,4)
    float mn = fminf(fminf(xn.x, xn.y), fminf(xn.z, xn.w));
    float mx = fmaxf(fmaxf(xn.x, xn.y), fmaxf(xn.z, xn.w));
#pragma unroll
    for (int m = 1; m <= 4; m <<= 1) { mn = fminf(mn, shflx(mn, m)); mx = fmaxf(mx, shflx(mx, m)); }
    float sc = 2.f / (mx - mn + 1e-8f);
    float4 nr = make_float4((xn.x - mn) * sc - 1.f, (xn.y - mn) * sc - 1.f,
                            (xn.z - mn) * sc - 1.f, (xn.w - mn) * sc - 1.f);

    // out accum: t[o] = nr . Mn[o][:] (+ xn . Rw[o][:]); butterfly within q bits
    const float4* M4 = (const float4*)Ms;
    const float4* R4 = (const float4*)Rs;
    float outA = 0.f, outB = 0.f;
#pragma unroll
    for (int o = 0; o < 10; ++o) {
        float4 m4 = M4[o * 8 + q];
        float t = nr.x * m4.x + nr.y * m4.y + nr.z * m4.z + nr.w * m4.w;
        if (israw) {
            float4 r4 = R4[o * 8 + q];
            t += xn.x * r4.x + xn.y * r4.y + xn.z * r4.z + xn.w * r4.w;
        }
        t += shflx(t, 1); t += shflx(t, 2); t += shflx(t, 4);
        if (o == q) outA = t;
        if (o == 8 + q) outB = t;
    }
    if (valid) {
        out[n * 10 + q] += outA;
        if (q < 2) out[n * 10 + 8 + q] += outB;
    }
}

extern "C" void kernel_launch(void* const* d_in, const int* in_sizes, int n_in,
                              void* d_out, int out_size, void* d_ws, size_t ws_size,
                              hipStream_t stream)
{
    const float* x  = (const float*)d_in[0];
    const int*   ei = (const int*)d_in[1];
    const float* W1 = (const float*)d_in[2];
    const float* b1 = (const float*)d_in[3];
    const float* Wc = (const float*)d_in[4];
    const float* bc = (const float*)d_in[5];
    const float* W2 = (const float*)d_in[6];
    const float* b2 = (const float*)d_in[7];
    float* out = (float*)d_out;

    const int N = in_sizes[0] / 64;
    const int E = in_sizes[1] / 2;
    const int M = N * NB;                     // (node,bucket) rows
    const int G1 = (N + (1 << CSH) - 1) >> CSH;   // 196 coarse bins (<=256)
    const int* src = ei;
    const int* dst = ei + E;

    char* ws = (char*)d_ws;
    size_t off = 0;
    auto alloc = [&](size_t bytes) -> void* {
        void* p = ws + off;
        off = (off + bytes + 255) & ~size_t(255);
        return p;
    };
    int*   gcnt    = (int*)alloc(256 * 4);
    int*   gptr    = (int*)alloc(257 * 4);
    int*   gcur    = (int*)alloc(256 * 4);
    int*   rp4     = (int*)alloc((size_t)(M + 1) * 4);
    float* dis     = (float*)alloc((size_t)N * 4);
    int*   tmp     = (int*)alloc((size_t)E * 4);
    int*   csr     = (int*)alloc((size_t)E * 4);
    float* hs_a    = (float*)alloc((size_t)N * 32 * 4);
    float* hs_b    = (float*)alloc((size_t)N * 32 * 4);
    float* Mn      = (float*)alloc(32 * 32 * 10 * 4);
    float* Rw      = (float*)alloc(32 * 32 * 10 * 4);

    hipMemsetAsync(gcnt, 0, 256 * 4, stream);
    k_chist<<<256, 256, 0, stream>>>(dst, E, gcnt, G1);
    k_cscan<<<1, 256, 0, stream>>>(gcnt, gptr, gcur, G1, E);
    k_cscatter<<<256, 256, 0, stream>>>(src, dst, E, gcur, tmp, G1);
    k_build<<<G1, 256, 0, stream>>>(tmp, gptr, rp4, csr, dis, N, M);
    k_mnorm<<<(32 * 32 * 10 + 255) / 256, 256, 0, stream>>>(W2, Mn, Rw);

    const int gb0 = (N + 3) / 4;
    k_x0<<<gb0, 256, 0, stream>>>(x, W1, b1, W2, b2, Mn, dis, hs_a, out, N);

    const int gb = (N + 31) / 32;             // 3125 blocks, 32 nodes each
    float* hin = hs_a; float* hout = hs_b;
    for (int j = 1; j <= 31; ++j) {
        int israw = (j == 1 || j == 16) ? 1 : 0;
        k_gcn<<<gb, 256, 0, stream>>>((const float4*)hin, (float4*)hout, dis, rp4,
                                      csr,
                                      Wc + (size_t)(j - 1) * 1024,
                                      bc + (size_t)(j - 1) * 32,
                                      Mn + (size_t)j * 320,
                                      Rw + (size_t)j * 320,
                                      out, N, israw);
        float* t = hin; hin = hout; hout = t;
    }
}

// Round 13
// 2081.788 us; speedup vs baseline: 1.0309x; 1.0309x over previous
//
#include <hip/hip_runtime.h>

// SDGCN32: 31-layer GCN, N=100k, E=3.2M, F=32.
//  - hs = dis*h carried FP32, row-major [n][32] (fp16 carrier fails 31-layer error amp)
//  - CSR per (dst, src-bucket), NB=4 (R7 optimum; NB=8 and NB=1 both worse)
//  - CSR built via two-level binning (R10: kills k_fill's 194MB partial-line write amp)
//  - k_gcn (R7, verbatim): wave = 8 nodes x 8 quads; lanes (i,0..7) walk node i's segment
//    in lockstep (one 128B line/edge, coalesced); register accumulation, unroll-4;
//    buckets swept in phase (__syncthreads) -> per-XCD L2 working set ~= one 4MiB chunk.
//  - k_x0 (R13): 8 nodes/block, wave = 2 nodes x 32 ch; x rows staged in LDS, W1
//    transposed [c][k] pad-68, float4 LDS dot (4 k-terms/instr). Butterflies per
//    32-lane half. Out-init uses R12's proven scalar pattern. (R11's 8-node/wave
//    float4-out version deterministically diverged on replays — still quarantined.)
//  - out accumulated online: out += mynorm(x_j)@Mn_j (+ raw x_j@Rw_j, j in {0,1,16})

#define NB 4        // src buckets
#define BSHIFT 15   // bucket = src >> 15 (32768 nodes = 4 MiB fp32 chunk)
#define CSH 9       // coarse bin = dst >> 9 (512 nodes)

__device__ __forceinline__ float shflx(float v, int m) { return __shfl_xor(v, m, 64); }

// ---------- pass A1: coarse histogram ----------
__global__ __launch_bounds__(256) void k_chist(const int* __restrict__ dst, int E,
                                               int* __restrict__ gcnt, int G1) {
    __shared__ int lh[256];
    lh[threadIdx.x] = 0;
    __syncthreads();
    int chunk = (E + gridDim.x - 1) / gridDim.x;
    int s0 = blockIdx.x * chunk, s1 = min(E, s0 + chunk);
    for (int e = s0 + threadIdx.x; e < s1; e += 256)
        atomicAdd(&lh[dst[e] >> CSH], 1);
    __syncthreads();
    if (threadIdx.x < G1 && lh[threadIdx.x])
        atomicAdd(&gcnt[threadIdx.x], lh[threadIdx.x]);
}

// ---------- pass A2: scan coarse bins (G1 <= 256) ----------
__global__ void k_cscan(const int* __restrict__ gcnt, int* __restrict__ gptr,
                        int* __restrict__ gcur, int G1, int E) {
    __shared__ int s[256];
    int t = threadIdx.x;
    int v = (t < G1) ? gcnt[t] : 0;
    s[t] = v;
    __syncthreads();
    for (int off = 1; off < 256; off <<= 1) {
        int tv = (t >= off) ? s[t - off] : 0;
        __syncthreads();
        s[t] += tv;
        __syncthreads();
    }
    if (t < G1) { int ex = s[t] - v; gptr[t] = ex; gcur[t] = ex; }
    if (t == 0) gptr[G1] = E;
}

// ---------- pass A3: reservation scatter of packed (src | ldst<<17) ----------
__global__ __launch_bounds__(256) void k_cscatter(const int* __restrict__ src,
                                                  const int* __restrict__ dst, int E,
                                                  int* __restrict__ gcur,
                                                  int* __restrict__ tmp, int G1) {
    __shared__ int lh[256], lc[256];
    lh[threadIdx.x] = 0;
    __syncthreads();
    int chunk = (E + gridDim.x - 1) / gridDim.x;
    int s0 = blockIdx.x * chunk, s1 = min(E, s0 + chunk);
    for (int e = s0 + threadIdx.x; e < s1; e += 256)
        atomicAdd(&lh[dst[e] >> CSH], 1);
    __syncthreads();
    if (threadIdx.x < G1) {
        int c = lh[threadIdx.x];
        lc[threadIdx.x] = c ? atomicAdd(&gcur[threadIdx.x], c) : 0;
    }
    __syncthreads();
    for (int e = s0 + threadIdx.x; e < s1; e += 256) {
        int d = dst[e];
        int pos = atomicAdd(&lc[d >> CSH], 1);
        tmp[pos] = src[e] | ((d & ((1 << CSH) - 1)) << 17);
    }
}

// ---------- pass B: per coarse group -> fine CSR (rp4, csr, dis) ----------
__global__ __launch_bounds__(256) void k_build(const int* __restrict__ tmp,
                                               const int* __restrict__ gptr,
                                               int* __restrict__ rp4,
                                               int* __restrict__ csr,
                                               float* __restrict__ dis,
                                               int N, int M) {
    __shared__ int h[2048];     // fine bins: 512 nodes x NB
    __shared__ int c[2048];
    __shared__ int s[256];
    int g = blockIdx.x;
    int gb = gptr[g], ge = gptr[g + 1];
    int t = threadIdx.x;
#pragma unroll
    for (int k = 0; k < 8; ++k) h[t * 8 + k] = 0;
    __syncthreads();
    for (int e = gb + t; e < ge; e += 256) {
        int w = tmp[e];
        int srcv = w & 0x1FFFF, ldst = w >> 17;
        atomicAdd(&h[ldst * NB + (srcv >> BSHIFT)], 1);
    }
    __syncthreads();
    int base8 = t * 8;
    int loc[8], sum = 0;
#pragma unroll
    for (int k = 0; k < 8; ++k) { loc[k] = h[base8 + k]; sum += loc[k]; }
    s[t] = sum;
    __syncthreads();
    for (int off = 1; off < 256; off <<= 1) {
        int tv = (t >= off) ? s[t - off] : 0;
        __syncthreads();
        s[t] += tv;
        __syncthreads();
    }
    int run = s[t] - sum;
    int rowbase = g * 2048;
#pragma unroll
    for (int k = 0; k < 8; ++k) {
        int i = base8 + k;
        c[i] = run;
        int ig = rowbase + i;
        if (ig <= M) rp4[ig] = gb + run;
        run += loc[k];
    }
    __syncthreads();
    for (int e = gb + t; e < ge; e += 256) {
        int w = tmp[e];
        int srcv = w & 0x1FFFF, ldst = w >> 17;
        int pos = atomicAdd(&c[ldst * NB + (srcv >> BSHIFT)], 1);
        csr[gb + pos] = srcv;
    }
    // degrees -> dis
    int nodebase = g << CSH;
    for (int ln = t; ln < (1 << CSH); ln += 256) {
        int n = nodebase + ln;
        if (n < N) {
            int d = h[ln * NB] + h[ln * NB + 1] + h[ln * NB + 2] + h[ln * NB + 3];
            dis[n] = rsqrtf((float)d + 1.0f);
        }
    }
    if (g == gridDim.x - 1 && t == 0) rp4[M] = ge;   // ge == E for last group
}

// ---------- coefficients, layout [j][o][c] ----------
__global__ void k_mnorm(const float* __restrict__ W2, float* __restrict__ Mn,
                        float* __restrict__ Rw) {
    int idx = blockIdx.x * blockDim.x + threadIdx.x;
    if (idx >= 32 * 32 * 10) return;
    int c = idx % 32, o = (idx / 32) % 10, j = idx / 320;
    float v = 0.f;
    if (j >= 2 && j != 16) v += W2[(32 * j + c) * 10 + o];
    if (j <= 29 && j != 14) v -= W2[(32 * (j + 2) + c) * 10 + o];
    Mn[idx] = v;
    Rw[idx] = (j == 0 || j == 1 || j == 16) ? W2[(32 * j + c) * 10 + o] : 0.f;
}

// ---------- layer 0 (R13): 8 nodes/block, wave = 2 nodes x 32 ch, LDS-staged ----------
__global__ __launch_bounds__(256) void k_x0(
    const float* __restrict__ x, const float* __restrict__ W1, const float* __restrict__ b1,
    const float* __restrict__ b2, const float* __restrict__ Mn0, const float* __restrict__ Rw0,
    const float* __restrict__ dis, float* __restrict__ hs, float* __restrict__ out, int N)
{
    __shared__ float Wt[32 * 68];      // W1 transposed [c][k], pad 68 (bank spread)
    __shared__ float xs[8 * 64];       // 8 staged x rows
    __shared__ float bs[32];
    __shared__ float Ms[320];          // Mn_0 [o][c]
    __shared__ float Rs[320];          // Rw_0 [o][c] = W2 block 0
    int t = threadIdx.x;
    for (int i = t; i < 2048; i += 256) {
        int k = i >> 5, cc = i & 31;
        Wt[cc * 68 + k] = W1[i];
    }
    for (int i = t; i < 320; i += 256) { Ms[i] = Mn0[i]; Rs[i] = Rw0[i]; }
    if (t < 32) bs[t] = b1[t];
    int base = blockIdx.x * 8;
    {
        int nf2 = (min(N - base, 8)) * 32;               // float2 count
        const float2* x2 = (const float2*)(x + (size_t)base * 64);
        float2* xs2 = (float2*)xs;
        for (int i = t; i < nf2; i += 256) xs2[i] = x2[i];
    }
    __syncthreads();

    int node8 = t >> 5, c = t & 31;
    int n = base + node8;
    if (n >= N) return;

    // 64-dot: xs broadcast (same addr per half) + Wt float4 (4-way conflict, 1.58x)
    const float4* xs4 = (const float4*)(xs + node8 * 64);
    const float4* Wt4 = (const float4*)(Wt + c * 68);
    float acc = bs[c];
#pragma unroll
    for (int k4 = 0; k4 < 16; ++k4) {
        float4 xv = xs4[k4];
        float4 wv = Wt4[k4];
        acc += xv.x * wv.x + xv.y * wv.y + xv.z * wv.z + xv.w * wv.w;
    }
    acc = fmaxf(acc, 0.f);

    // mynorm over this node's 32 channels (butterfly stays within 32-lane half)
    float mn = acc, mx = acc;
#pragma unroll
    for (int m = 1; m <= 16; m <<= 1) { mn = fminf(mn, shflx(mn, m)); mx = fmaxf(mx, shflx(mx, m)); }
    float x0 = 2.f * (acc - mn) / (mx - mn + 1e-8f) - 1.f;
    float dn = dis[n];
    hs[(size_t)n * 32 + c] = dn * x0;                    // 2x128B coalesced per wave

    float mn2 = x0, mx2 = x0;
#pragma unroll
    for (int m = 1; m <= 16; m <<= 1) { mn2 = fminf(mn2, shflx(mn2, m)); mx2 = fmaxf(mx2, shflx(mx2, m)); }
    float n0 = 2.f * (x0 - mn2) / (mx2 - mn2 + 1e-8f) - 1.f;

    // out init: out[n][o] = b2[o] + x0.Rw0[o][:] + n0.Mn0[o][:]
    float outv = 0.f;
#pragma unroll
    for (int o = 0; o < 10; ++o) {
        float to = x0 * Rs[o * 32 + c] + n0 * Ms[o * 32 + c];
#pragma unroll
        for (int m = 1; m <= 16; m <<= 1) to += shflx(to, m);
        if (c == o) outv = to;
    }
    if (c < 10) out[(size_t)n * 10 + c] = b2[c] + outv;
}

// ---------- GCN layer: register-acc bucketed gather + parallel epilogue (R7) ----------
__global__ __launch_bounds__(256) void k_gcn(
    const float4* __restrict__ hs_in, float4* __restrict__ hs_out,
    const float* __restrict__ dis, const int* __restrict__ rp4,
    const int* __restrict__ csr,
    const float* __restrict__ W, const float* __restrict__ b,
    const float* __restrict__ Mn, const float* __restrict__ Rw,
    float* __restrict__ out, int N, int israw)
{
    __shared__ float Ws[1024];   // W [k][c]
    __shared__ float bs[32];
    __shared__ float Ms[320];    // Mn_j [o][c]
    __shared__ float Rs[320];    // Rw_j [o][c]
    for (int i = threadIdx.x; i < 1024; i += 256) Ws[i] = W[i];
    for (int i = threadIdx.x; i < 320; i += 256) { Ms[i] = Mn[i]; Rs[i] = Rw[i]; }
    if (threadIdx.x < 32) bs[threadIdx.x] = b[threadIdx.x];
    __syncthreads();

    int lane = threadIdx.x & 63;
    int q = lane & 7;            // channel quad c = 4q..4q+3
    int i8 = lane >> 3;          // node-sub 0..7
    int wave = threadIdx.x >> 6;
    int n = blockIdx.x * 32 + wave * 8 + i8;
    bool valid = (n < N);
    int nn = valid ? n : (N - 1);       // clamp: extra harmless loads only

    // self-loop term; lanes (i,0..7) -> 8 consecutive 128B rows = 1KB coalesced
    float4 acc = hs_in[(size_t)nn * 8 + q];

    int rbase = nn * NB;
    int rs = rp4[rbase];
    for (int p = 0; p < NB; ++p) {
        int re = rp4[rbase + p + 1];    // segment continuity: next rs = this re
        int e = rs;
        for (; e + 3 < re; e += 4) {
            int s0 = csr[e], s1 = csr[e + 1], s2 = csr[e + 2], s3 = csr[e + 3];
            float4 v0 = hs_in[(size_t)s0 * 8 + q];
            float4 v1 = hs_in[(size_t)s1 * 8 + q];
            float4 v2 = hs_in[(size_t)s2 * 8 + q];
            float4 v3 = hs_in[(size_t)s3 * 8 + q];
            acc.x += v0.x; acc.y += v0.y; acc.z += v0.z; acc.w += v0.w;
            acc.x += v1.x; acc.y += v1.y; acc.z += v1.z; acc.w += v1.w;
            acc.x += v2.x; acc.y += v2.y; acc.z += v2.z; acc.w += v2.w;
            acc.x += v3.x; acc.y += v3.y; acc.z += v3.z; acc.w += v3.w;
        }
        if (e + 1 < re) {
            int s0 = csr[e], s1 = csr[e + 1];
            float4 v0 = hs_in[(size_t)s0 * 8 + q];
            float4 v1 = hs_in[(size_t)s1 * 8 + q];
            acc.x += v0.x; acc.y += v0.y; acc.z += v0.z; acc.w += v0.w;
            acc.x += v1.x; acc.y += v1.y; acc.z += v1.z; acc.w += v1.w;
            e += 2;
        }
        if (e < re) {
            int s0 = csr[e];
            float4 v0 = hs_in[(size_t)s0 * 8 + q];
            acc.x += v0.x; acc.y += v0.y; acc.z += v0.z; acc.w += v0.w;
        }
        rs = re;
        __syncthreads();         // bucket phase alignment (uniform: all threads loop NB times)
    }

    float dn = dis[nn];
    float4 g = make_float4(dn * acc.x, dn * acc.y, dn * acc.z, dn * acc.w);

    // GEMM: xn[quad q of node i] = b + sum_k g_i[k] * W[k][4q..4q+3]
    const float4* W4 = (const float4*)Ws;
    float4 bb = ((const float4*)bs)[q];
    float4 xn = bb;
    int ibase = lane & 0x38;     // i8<<3
#pragma unroll
    for (int kp = 0; kp < 8; ++kp) {
        int sl = ibase | kp;     // lane holding quad kp of node i
        float gx = __shfl(g.x, sl, 64);
        float gy = __shfl(g.y, sl, 64);
        float gz = __shfl(g.z, sl, 64);
        float gw = __shfl(g.w, sl, 64);
        float4 w0 = W4[(kp * 4 + 0) * 8 + q];
        float4 w1 = W4[(kp * 4 + 1) * 8 + q];
        float4 w2 = W4[(kp * 4 + 2) * 8 + q];
        float4 w3 = W4[(kp * 4 + 3) * 8 + q];
        xn.x += gx * w0.x + gy * w1.x + gz * w2.x + gw * w3.x;
        xn.y += gx * w0.y + gy * w1.y + gz * w2.y + gw * w3.y;
        xn.z += gx * w0.z + gy * w1.z + gz * w2.z + gw * w3.z;
        xn.w += gx * w0.w + gy * w1.w + gz * w2.w + gw * w3.w;
    }

    if (valid)
        hs_out[(size_t)n * 8 + q] = make_float4(dn * xn.x, dn * xn.y, dn * xn.z, dn * xn.w);

    // mynorm over node's 32 channels: local 4, then butterfly over q bits (1,2,4)
    float mn = fminf(fminf(xn.x, xn.y), fminf(xn.z, xn.w));
    float mx = fmaxf(fmaxf(xn.x, xn.y), fmaxf(xn.z, xn.w));
#pragma unroll
    for (int m = 1; m <= 4; m <<= 1) { mn = fminf(mn, shflx(mn, m)); mx = fmaxf(mx, shflx(mx, m)); }
    float sc = 2.f / (mx - mn + 1e-8f);
    float4 nr = make_float4((xn.x - mn) * sc - 1.f, (xn.y - mn) * sc - 1.f,
                            (xn.z - mn) * sc - 1.f, (xn.w - mn) * sc - 1.f);

    // out accum: t[o] = nr . Mn[o][:] (+ xn . Rw[o][:]); butterfly within q bits
    const float4* M4 = (const float4*)Ms;
    const float4* R4 = (const float4*)Rs;
    float outA = 0.f, outB = 0.f;
#pragma unroll
    for (int o = 0; o < 10; ++o) {
        float4 m4 = M4[o * 8 + q];
        float t = nr.x * m4.x + nr.y * m4.y + nr.z * m4.z + nr.w * m4.w;
        if (israw) {
            float4 r4 = R4[o * 8 + q];
            t += xn.x * r4.x + xn.y * r4.y + xn.z * r4.z + xn.w * r4.w;
        }
        t += shflx(t, 1); t += shflx(t, 2); t += shflx(t, 4);
        if (o == q) outA = t;
        if (o == 8 + q) outB = t;
    }
    if (valid) {
        out[n * 10 + q] += outA;
        if (q < 2) out[n * 10 + 8 + q] += outB;
    }
}

extern "C" void kernel_launch(void* const* d_in, const int* in_sizes, int n_in,
                              void* d_out, int out_size, void* d_ws, size_t ws_size,
                              hipStream_t stream)
{
    const float* x  = (const float*)d_in[0];
    const int*   ei = (const int*)d_in[1];
    const float* W1 = (const float*)d_in[2];
    const float* b1 = (const float*)d_in[3];
    const float* Wc = (const float*)d_in[4];
    const float* bc = (const float*)d_in[5];
    const float* W2 = (const float*)d_in[6];
    const float* b2 = (const float*)d_in[7];
    float* out = (float*)d_out;

    const int N = in_sizes[0] / 64;
    const int E = in_sizes[1] / 2;
    const int M = N * NB;                     // (node,bucket) rows
    const int G1 = (N + (1 << CSH) - 1) >> CSH;   // 196 coarse bins (<=256)
    const int* src = ei;
    const int* dst = ei + E;

    char* ws = (char*)d_ws;
    size_t off = 0;
    auto alloc = [&](size_t bytes) -> void* {
        void* p = ws + off;
        off = (off + bytes + 255) & ~size_t(255);
        return p;
    };
    int*   gcnt    = (int*)alloc(256 * 4);
    int*   gptr    = (int*)alloc(257 * 4);
    int*   gcur    = (int*)alloc(256 * 4);
    int*   rp4     = (int*)alloc((size_t)(M + 1) * 4);
    float* dis     = (float*)alloc((size_t)N * 4);
    int*   tmp     = (int*)alloc((size_t)E * 4);
    int*   csr     = (int*)alloc((size_t)E * 4);
    float* hs_a    = (float*)alloc((size_t)N * 32 * 4);
    float* hs_b    = (float*)alloc((size_t)N * 32 * 4);
    float* Mn      = (float*)alloc(32 * 32 * 10 * 4);
    float* Rw      = (float*)alloc(32 * 32 * 10 * 4);

    hipMemsetAsync(gcnt, 0, 256 * 4, stream);
    k_chist<<<256, 256, 0, stream>>>(dst, E, gcnt, G1);
    k_cscan<<<1, 256, 0, stream>>>(gcnt, gptr, gcur, G1, E);
    k_cscatter<<<256, 256, 0, stream>>>(src, dst, E, gcur, tmp, G1);
    k_build<<<G1, 256, 0, stream>>>(tmp, gptr, rp4, csr, dis, N, M);
    k_mnorm<<<(32 * 32 * 10 + 255) / 256, 256, 0, stream>>>(W2, Mn, Rw);

    const int gb0 = (N + 7) / 8;              // 12500 blocks, 8 nodes each
    k_x0<<<gb0, 256, 0, stream>>>(x, W1, b1, b2, Mn, Rw, dis, hs_a, out, N);

    const int gb = (N + 31) / 32;             // 3125 blocks, 32 nodes each
    float* hin = hs_a; float* hout = hs_b;
    for (int j = 1; j <= 31; ++j) {
        int israw = (j == 1 || j == 16) ? 1 : 0;
        k_gcn<<<gb, 256, 0, stream>>>((const float4*)hin, (float4*)hout, dis, rp4,
                                      csr,
                                      Wc + (size_t)(j - 1) * 1024,
                                      bc + (size_t)(j - 1) * 32,
                                      Mn + (size_t)j * 320,
                                      Rw + (size_t)j * 320,
                                      out, N, israw);
        float* t = hin; hin = hout; hout = t;
    }
}